// Round 6
// baseline (198.095 us; speedup 1.0000x reference)
//
#include <hip/hip_runtime.h>
#include <stdint.h>
#include <stddef.h>

// gcnmask: N=50000, DEG=16, F=128. Edges grouped by dst (dst = e/16) -> no atomics.
// R6: latency-filling. edge_k 2-stage node pipeline (double-buffered gathers);
//     final_k 4-node interleave; zy_k LDS-transposed coalesced epilogue;
//     -log2e folded into packed Wm.

#define NNODES 50000
#define DEG    16
#define FD     128

#define NEG_LOG2E -1.44269504f

typedef __bf16 bf16x8 __attribute__((ext_vector_type(8)));
typedef short  s16x8  __attribute__((ext_vector_type(8)));
typedef float  f32x4  __attribute__((ext_vector_type(4)));
typedef float  f32x2  __attribute__((ext_vector_type(2)));

__device__ __forceinline__ short f2bf_s(float f) {
    union { float f; uint32_t u; } v; v.f = f;
    uint32_t r = v.u + 0x7fffu + ((v.u >> 16) & 1u);   // RNE
    return (short)(r >> 16);
}
__device__ __forceinline__ float bflo(uint32_t u) {    // low bf16 -> f32
    union { uint32_t u; float f; } v; v.u = u << 16;
    return v.f;
}
__device__ __forceinline__ float bfhi(uint32_t u) {    // high bf16 -> f32
    union { uint32_t u; float f; } v; v.u = u & 0xffff0000u;
    return v.f;
}

// Pack Wmb[k][c] (c<128: Wm_top; c>=128: Wm_bot), PRE-SCALED by -log2e (both halves feed
// only the sigmoid exponent), and weight[128x128] (unscaled) into bf16 B-fragment order:
//   idx = ((kk*NT + ntile)*64 + q*16 + n15)*8 + (k&7).
__global__ __launch_bounds__(256) void pack_k(const float* __restrict__ wm,
                                              const float* __restrict__ w,
                                              short* __restrict__ wmb,
                                              short* __restrict__ wpack) {
    int tid = blockIdx.x * 256 + threadIdx.x;
    if (tid < 128 * 256) {
        int k = tid >> 8, c = tid & 255;
        float v = (c < 128) ? wm[k * 128 + c] : wm[(128 + k) * 128 + (c - 128)];
        int idx = (((k >> 5) * 16 + (c >> 4)) * 64 + ((k >> 3) & 3) * 16 + (c & 15)) * 8 + (k & 7);
        wmb[idx] = f2bf_s(NEG_LOG2E * v);
    }
    if (tid < 128 * 128) {
        int k = tid >> 7, n = tid & 127;
        int idx = (((k >> 5) * 8 + (n >> 4)) * 64 + ((k >> 3) & 3) * 16 + (n & 15)) * 8 + (k & 7);
        wpack[idx] = f2bf_s(w[tid]);
    }
}

// ZY' = x @ Wmb' ([50000x128]@[128x256], pre-scaled). Block = 16 nodes, 4 waves.
// Epilogue: stage C-tile [16 x 256] in LDS, then coalesced write-out:
//   c<128 -> zbf (bf16 pairs); c>=128 -> xy = bf16(x) | bf16(y')<<16.
__global__ __launch_bounds__(256) void zy_k(const float* __restrict__ x,
                                            const short* __restrict__ wmb,
                                            short* __restrict__ zbf,
                                            uint32_t* __restrict__ xy) {
    __shared__ float ct[16 * 260];                     // 16.6 KB, stride 260 (1040 B, 16B-aligned rows)
    const int tid = threadIdx.x, wave = tid >> 6, lane = tid & 63;
    const int q = lane >> 4, m = lane & 15;
    const int node0 = blockIdx.x * 16;

    f32x4 acc[4];
    #pragma unroll
    for (int nt = 0; nt < 4; ++nt) acc[nt] = (f32x4){0.f, 0.f, 0.f, 0.f};

    #pragma unroll
    for (int kk = 0; kk < 4; ++kk) {
        const float* rp = x + (size_t)(node0 + m) * FD + kk * 32 + q * 8;
        f32x4 lo = *reinterpret_cast<const f32x4*>(rp);
        f32x4 hi = *reinterpret_cast<const f32x4*>(rp + 4);
        bf16x8 a;
        a[0]=(__bf16)lo.x; a[1]=(__bf16)lo.y; a[2]=(__bf16)lo.z; a[3]=(__bf16)lo.w;
        a[4]=(__bf16)hi.x; a[5]=(__bf16)hi.y; a[6]=(__bf16)hi.z; a[7]=(__bf16)hi.w;
        #pragma unroll
        for (int nt = 0; nt < 4; ++nt) {
            int frag = kk * 16 + wave * 4 + nt;
            s16x8 braw = *reinterpret_cast<const s16x8*>(wmb + ((size_t)frag * 64 + lane) * 8);
            acc[nt] = __builtin_amdgcn_mfma_f32_16x16x32_bf16(a, __builtin_bit_cast(bf16x8, braw), acc[nt], 0, 0, 0);
        }
    }
    // stage C: col = (wave*4+nt)*16 + m, row = q*4 + i
    #pragma unroll
    for (int nt = 0; nt < 4; ++nt)
        #pragma unroll
        for (int i = 0; i < 4; ++i)
            ct[(q * 4 + i) * 260 + wave * 64 + nt * 16 + m] = acc[nt][i];
    __syncthreads();

    const int row = tid >> 4;                 // 0..15
    const int c0  = (tid & 15) * 16;          // 0..240
    const int grow = node0 + row;
    if (c0 < 128) {
        uint32_t zo[8];
        #pragma unroll
        for (int j = 0; j < 8; ++j) {
            float v0 = ct[row * 260 + c0 + 2 * j];
            float v1 = ct[row * 260 + c0 + 2 * j + 1];
            zo[j] = (uint32_t)(uint16_t)f2bf_s(v0) | ((uint32_t)(uint16_t)f2bf_s(v1) << 16);
        }
        uint4* dst = reinterpret_cast<uint4*>(zbf + (size_t)grow * FD + c0);
        dst[0] = make_uint4(zo[0], zo[1], zo[2], zo[3]);
        dst[1] = make_uint4(zo[4], zo[5], zo[6], zo[7]);
    } else {
        const int f0 = c0 - 128;
        const float* xr = x + (size_t)grow * FD + f0;   // L1-hot (A-frags read these rows)
        uint4* dst = reinterpret_cast<uint4*>(xy + (size_t)grow * FD + f0);
        #pragma unroll
        for (int v = 0; v < 4; ++v) {
            uint32_t xo[4];
            #pragma unroll
            for (int j = 0; j < 4; ++j) {
                float yv = ct[row * 260 + c0 + v * 4 + j];
                float xv = xr[v * 4 + j];
                xo[j] = (uint32_t)(uint16_t)f2bf_s(xv) | ((uint32_t)(uint16_t)f2bf_s(yv) << 16);
            }
            dst[v] = make_uint4(xo[0], xo[1], xo[2], xo[3]);
        }
    }
}

// Block = 256 thr = 4 waves x 4 nodes each, lane owns features 2*lane, 2*lane+1.
// 2-stage pipeline: gathers for node mt+1 (16 uint2 + z + center) issue while node mt computes.
// mask = rcp(1+exp2(z'+y')); agg += mask*x; x_new -> LDS; support[16x128] = x_new @ weight.
__global__ __launch_bounds__(256) void edge_k(const short* __restrict__ zbf,
                                              const uint32_t* __restrict__ xy,
                                              const int* __restrict__ esrc,
                                              const short* __restrict__ wpack,
                                              short* __restrict__ support) {
    __shared__ float xn[16 * 132];
    const int tid = threadIdx.x, wave = tid >> 6, lane = tid & 63;
    const int q = lane >> 4, m = lane & 15;
    const int node0 = blockIdx.x * 16;
    const int nu0 = __builtin_amdgcn_readfirstlane(node0 + wave * 4);

    uint2     buf[2][16];
    uint2     cr[2];
    uint32_t  zr[2];

    // prologue: issue node 0
    {
        const int* ep = esrc + nu0 * DEG;
        #pragma unroll
        for (int e = 0; e < 16; ++e)
            buf[0][e] = reinterpret_cast<const uint2*>(xy + (size_t)ep[e] * FD)[lane];
        zr[0] = reinterpret_cast<const uint32_t*>(zbf + (size_t)nu0 * FD)[lane];
        cr[0] = reinterpret_cast<const uint2*>(xy + (size_t)nu0 * FD)[lane];
    }

    #pragma unroll
    for (int mt = 0; mt < 4; ++mt) {
        const int cur = mt & 1, nxt = cur ^ 1;
        if (mt < 3) {   // issue node mt+1 while computing mt
            const int nun = nu0 + mt + 1;
            const int* ep = esrc + nun * DEG;
            #pragma unroll
            for (int e = 0; e < 16; ++e)
                buf[nxt][e] = reinterpret_cast<const uint2*>(xy + (size_t)ep[e] * FD)[lane];
            zr[nxt] = reinterpret_cast<const uint32_t*>(zbf + (size_t)nun * FD)[lane];
            cr[nxt] = reinterpret_cast<const uint2*>(xy + (size_t)nun * FD)[lane];
        }
        const float zn0 = bflo(zr[cur]), zn1 = bfhi(zr[cur]);
        float a0a = 0.f, a0b = 0.f, a1a = 0.f, a1b = 0.f;
        #pragma unroll
        for (int e = 0; e < 16; ++e) {
            uint2 u = buf[cur][e];
            float g0 = __builtin_amdgcn_rcpf(1.f + __builtin_amdgcn_exp2f(zn0 + bfhi(u.x)));
            float g1 = __builtin_amdgcn_rcpf(1.f + __builtin_amdgcn_exp2f(zn1 + bfhi(u.y)));
            if (e & 1) { a0b += g0 * bflo(u.x); a1b += g1 * bflo(u.y); }
            else       { a0a += g0 * bflo(u.x); a1a += g1 * bflo(u.y); }
        }
        f32x2 xv;
        xv.x = bflo(cr[cur].x) + a0a + a0b;
        xv.y = bflo(cr[cur].y) + a1a + a1b;
        *reinterpret_cast<f32x2*>(&xn[(wave * 4 + mt) * 132 + 2 * lane]) = xv;
    }
    __syncthreads();

    // support = xn[16x128] @ weight; wave w -> ntiles 2w, 2w+1
    f32x4 sacc[2];
    sacc[0] = (f32x4){0.f, 0.f, 0.f, 0.f};
    sacc[1] = (f32x4){0.f, 0.f, 0.f, 0.f};
    #pragma unroll
    for (int kk = 0; kk < 4; ++kk) {
        const float* p = &xn[m * 132 + kk * 32 + q * 8];
        bf16x8 a;
        a[0]=(__bf16)p[0]; a[1]=(__bf16)p[1]; a[2]=(__bf16)p[2]; a[3]=(__bf16)p[3];
        a[4]=(__bf16)p[4]; a[5]=(__bf16)p[5]; a[6]=(__bf16)p[6]; a[7]=(__bf16)p[7];
        #pragma unroll
        for (int t = 0; t < 2; ++t) {
            int nt = wave * 2 + t;
            s16x8 braw = *reinterpret_cast<const s16x8*>(wpack + ((size_t)(kk * 8 + nt) * 64 + lane) * 8);
            sacc[t] = __builtin_amdgcn_mfma_f32_16x16x32_bf16(a, __builtin_bit_cast(bf16x8, braw), sacc[t], 0, 0, 0);
        }
    }
    #pragma unroll
    for (int t = 0; t < 2; ++t) {
        int nt = wave * 2 + t;
        #pragma unroll
        for (int i = 0; i < 4; ++i)
            support[(size_t)(node0 + q * 4 + i) * FD + nt * 16 + m] = f2bf_s(sacc[t][i]);
    }
}

// Wave handles 4 nodes interleaved in the e-loop (4 independent gathers in flight per step).
// Scalarized esrc/adj (SGPR); lane owns features 2*lane, 2*lane+1.
__global__ __launch_bounds__(256) void final_k(const short* __restrict__ support,
                                               const float* __restrict__ adj,
                                               const int* __restrict__ esrc,
                                               const float* __restrict__ bias,
                                               float* __restrict__ out) {
    const int tid = threadIdx.x, wave = tid >> 6, lane = tid & 63;
    const int n0 = blockIdx.x * 16 + wave * 4;
    f32x2 b = *reinterpret_cast<const f32x2*>(bias + 2 * lane);

    int nu[4];
    const int* ep[4];
    const float* ap[4];
    #pragma unroll
    for (int t = 0; t < 4; ++t) {
        nu[t] = __builtin_amdgcn_readfirstlane(n0 + t);
        ep[t] = esrc + nu[t] * DEG;
        ap[t] = adj + nu[t] * DEG;
    }
    float a0[4], a1[4];
    #pragma unroll
    for (int t = 0; t < 4; ++t) { a0[t] = b.x; a1[t] = b.y; }

    #pragma unroll
    for (int e = 0; e < 16; ++e) {
        #pragma unroll
        for (int t = 0; t < 4; ++t) {
            int s = ep[t][e];
            float w = ap[t][e];
            uint32_t u = reinterpret_cast<const uint32_t*>(support + (size_t)s * FD)[lane];
            a0[t] += w * bflo(u);
            a1[t] += w * bfhi(u);
        }
    }
    #pragma unroll
    for (int t = 0; t < 4; ++t) {
        f32x2 r; r.x = a0[t]; r.y = a1[t];
        *reinterpret_cast<f32x2*>(out + (size_t)nu[t] * FD + 2 * lane) = r;
    }
}

extern "C" void kernel_launch(void* const* d_in, const int* in_sizes, int n_in,
                              void* d_out, int out_size, void* d_ws, size_t ws_size,
                              hipStream_t stream) {
    const float* x      = (const float*)d_in[0];
    const float* weight = (const float*)d_in[1];
    const float* bias   = (const float*)d_in[2];
    const float* wm     = (const float*)d_in[3];
    const float* adj    = (const float*)d_in[4];
    const int*   esrc   = (const int*)d_in[5];
    // d_in[6] edge_dst unused: dst(e) = e/16 by construction.

    // ws: [0,64K) Wmb packed | [64K,96K) weight packed | [96K,+12.8M) Zbf | then support bf16.
    // XY (uint per (node,f): low=bf16(x), high=bf16(-log2e*Y)) lives in d_out, fully consumed
    // by edge_k before final_k overwrites d_out with the real output.
    short*    wmb     = (short*)d_ws;
    short*    wpack   = (short*)((char*)d_ws + 65536);
    short*    zbf     = (short*)((char*)d_ws + 98304);
    short*    support = (short*)((char*)d_ws + 98304 + (size_t)NNODES * FD * 2);
    uint32_t* xy      = (uint32_t*)d_out;
    float*    out     = (float*)d_out;

    pack_k <<<128,         256, 0, stream>>>(wm, weight, wmb, wpack);
    zy_k   <<<NNODES / 16, 256, 0, stream>>>(x, wmb, zbf, xy);
    edge_k <<<NNODES / 16, 256, 0, stream>>>(zbf, xy, esrc, wpack, support);
    final_k<<<NNODES / 16, 256, 0, stream>>>(support, adj, esrc, bias, out);
}

// Round 8
// 180.262 us; speedup vs baseline: 1.0989x; 1.0989x over previous
//
#include <hip/hip_runtime.h>
#include <stdint.h>
#include <stddef.h>

// gcnmask: N=50000, DEG=16, F=128. Edges grouped by dst (dst = e/16) -> no atomics.
// R8: R7 structure (no support pass; edge_k = pure gather+sigmoid; out_k = gather+GEMM+bias)
//     with accuracy fix: gathered payload split into xb (bf16 x, 256 B/row) + y8 (fp8 y',
//     128 B/row). fp8 only on the sigmoid exponent (self-limiting error); x stays bf16.

#define NNODES 50000
#define DEG    16
#define FD     128

#define NEG_LOG2E -1.44269504f

typedef __bf16 bf16x8 __attribute__((ext_vector_type(8)));
typedef short  s16x8  __attribute__((ext_vector_type(8)));
typedef float  f32x4  __attribute__((ext_vector_type(4)));
typedef float  f32x2  __attribute__((ext_vector_type(2)));

__device__ __forceinline__ short f2bf_s(float f) {
    union { float f; uint32_t u; } v; v.f = f;
    uint32_t r = v.u + 0x7fffu + ((v.u >> 16) & 1u);   // RNE
    return (short)(r >> 16);
}
__device__ __forceinline__ float bflo(uint32_t u) {
    union { uint32_t u; float f; } v; v.u = u << 16;
    return v.f;
}
__device__ __forceinline__ float bfhi(uint32_t u) {
    union { uint32_t u; float f; } v; v.u = u & 0xffff0000u;
    return v.f;
}

// Pack Wmb[k][c] (c<128: Wm_top; c>=128: Wm_bot), PRE-SCALED by -log2e, and weight
// (unscaled) into bf16 B-fragment order: idx = ((kk*NT+ntile)*64 + q*16 + n15)*8 + (k&7).
__global__ __launch_bounds__(256) void pack_k(const float* __restrict__ wm,
                                              const float* __restrict__ w,
                                              short* __restrict__ wmb,
                                              short* __restrict__ wpack) {
    int tid = blockIdx.x * 256 + threadIdx.x;
    if (tid < 128 * 256) {
        int k = tid >> 8, c = tid & 255;
        float v = (c < 128) ? wm[k * 128 + c] : wm[(128 + k) * 128 + (c - 128)];
        int idx = (((k >> 5) * 16 + (c >> 4)) * 64 + ((k >> 3) & 3) * 16 + (c & 15)) * 8 + (k & 7);
        wmb[idx] = f2bf_s(NEG_LOG2E * v);
    }
    if (tid < 128 * 128) {
        int k = tid >> 7, n = tid & 127;
        int idx = (((k >> 5) * 8 + (n >> 4)) * 64 + ((k >> 3) & 3) * 16 + (n & 15)) * 8 + (k & 7);
        wpack[idx] = f2bf_s(w[tid]);
    }
}

// ZY' = x @ Wmb' ([50000x128]@[128x256]). Block = 16 nodes, 4 waves.
// Epilogue via LDS transpose, coalesced writes:
//   c<128  -> zbf bf16 pairs (z' rows)
//   c>=128 -> xb bf16 pairs (x rows, 256 B) + y8 fp8 (y' rows, 128 B)
__global__ __launch_bounds__(256) void zy_k(const float* __restrict__ x,
                                            const short* __restrict__ wmb,
                                            short* __restrict__ zbf,
                                            uint32_t* __restrict__ xb,
                                            uint8_t* __restrict__ y8) {
    __shared__ float ct[16 * 260];
    const int tid = threadIdx.x, wave = tid >> 6, lane = tid & 63;
    const int q = lane >> 4, m = lane & 15;
    const int node0 = blockIdx.x * 16;

    f32x4 acc[4];
    #pragma unroll
    for (int nt = 0; nt < 4; ++nt) acc[nt] = (f32x4){0.f, 0.f, 0.f, 0.f};

    #pragma unroll
    for (int kk = 0; kk < 4; ++kk) {
        const float* rp = x + (size_t)(node0 + m) * FD + kk * 32 + q * 8;
        f32x4 lo = *reinterpret_cast<const f32x4*>(rp);
        f32x4 hi = *reinterpret_cast<const f32x4*>(rp + 4);
        bf16x8 a;
        a[0]=(__bf16)lo.x; a[1]=(__bf16)lo.y; a[2]=(__bf16)lo.z; a[3]=(__bf16)lo.w;
        a[4]=(__bf16)hi.x; a[5]=(__bf16)hi.y; a[6]=(__bf16)hi.z; a[7]=(__bf16)hi.w;
        #pragma unroll
        for (int nt = 0; nt < 4; ++nt) {
            int frag = kk * 16 + wave * 4 + nt;
            s16x8 braw = *reinterpret_cast<const s16x8*>(wmb + ((size_t)frag * 64 + lane) * 8);
            acc[nt] = __builtin_amdgcn_mfma_f32_16x16x32_bf16(a, __builtin_bit_cast(bf16x8, braw), acc[nt], 0, 0, 0);
        }
    }
    #pragma unroll
    for (int nt = 0; nt < 4; ++nt)
        #pragma unroll
        for (int i = 0; i < 4; ++i)
            ct[(q * 4 + i) * 260 + wave * 64 + nt * 16 + m] = acc[nt][i];
    __syncthreads();

    const int row = tid >> 4;                 // 0..15
    const int c0  = (tid & 15) * 16;          // 0..240
    const int grow = node0 + row;
    if (c0 < 128) {
        uint32_t zo[8];
        #pragma unroll
        for (int j = 0; j < 8; ++j) {
            float v0 = ct[row * 260 + c0 + 2 * j];
            float v1 = ct[row * 260 + c0 + 2 * j + 1];
            zo[j] = (uint32_t)(uint16_t)f2bf_s(v0) | ((uint32_t)(uint16_t)f2bf_s(v1) << 16);
        }
        uint4* dst = reinterpret_cast<uint4*>(zbf + (size_t)grow * FD + c0);
        dst[0] = make_uint4(zo[0], zo[1], zo[2], zo[3]);
        dst[1] = make_uint4(zo[4], zo[5], zo[6], zo[7]);
    } else {
        const int f0 = c0 - 128;
        const float* xr = x + (size_t)grow * FD + f0;   // L1-hot
        // x -> bf16 pairs (8 uints)
        uint32_t xo[8];
        #pragma unroll
        for (int j = 0; j < 8; ++j) {
            float v0 = xr[2 * j], v1 = xr[2 * j + 1];
            xo[j] = (uint32_t)(uint16_t)f2bf_s(v0) | ((uint32_t)(uint16_t)f2bf_s(v1) << 16);
        }
        uint4* xdst = reinterpret_cast<uint4*>(xb + (size_t)grow * 64 + f0 / 2);
        xdst[0] = make_uint4(xo[0], xo[1], xo[2], xo[3]);
        xdst[1] = make_uint4(xo[4], xo[5], xo[6], xo[7]);
        // y' -> fp8 (16 bytes = 4 dwords)
        uint32_t yo[4];
        #pragma unroll
        for (int g = 0; g < 4; ++g) {
            float y0 = ct[row * 260 + c0 + 4 * g];
            float y1 = ct[row * 260 + c0 + 4 * g + 1];
            float y2 = ct[row * 260 + c0 + 4 * g + 2];
            float y3 = ct[row * 260 + c0 + 4 * g + 3];
            int u = __builtin_amdgcn_cvt_pk_fp8_f32(y0, y1, 0, false);
            u     = __builtin_amdgcn_cvt_pk_fp8_f32(y2, y3, u, true);
            yo[g] = (uint32_t)u;
        }
        *reinterpret_cast<uint4*>(y8 + (size_t)grow * 128 + f0) = make_uint4(yo[0], yo[1], yo[2], yo[3]);
    }
}

// Pure gather+sigmoid (no LDS/barrier). Block = 4 waves x 4 nodes; lane owns features
// 2*lane, 2*lane+1; nodes processed in interleaved pairs for memory ILP.
// x_new = x + sum_e sigmoid(z'+y'[src])*x[src] -> xnb bf16 rows (256 B, coalesced).
__global__ __launch_bounds__(256) void edge_k(const short* __restrict__ zbf,
                                              const uint32_t* __restrict__ xb,
                                              const uint8_t* __restrict__ y8,
                                              const int* __restrict__ esrc,
                                              uint32_t* __restrict__ xnb) {
    const int tid = threadIdx.x, wave = tid >> 6, lane = tid & 63;
    const int wn0 = blockIdx.x * 16 + wave * 4;

    #pragma unroll
    for (int pr = 0; pr < 2; ++pr) {
        const int nuA = __builtin_amdgcn_readfirstlane(wn0 + pr * 2);
        const int nuB = __builtin_amdgcn_readfirstlane(wn0 + pr * 2 + 1);
        const int* epA = esrc + nuA * DEG;             // uniform -> s_load_dwordx16
        const int* epB = esrc + nuB * DEG;
        uint32_t zA = reinterpret_cast<const uint32_t*>(zbf + (size_t)nuA * FD)[lane];
        uint32_t zB = reinterpret_cast<const uint32_t*>(zbf + (size_t)nuB * FD)[lane];
        uint32_t cAw = xb[(size_t)nuA * 64 + lane];
        uint32_t cBw = xb[(size_t)nuB * 64 + lane];
        const float zA0 = bflo(zA), zA1 = bfhi(zA);
        const float zB0 = bflo(zB), zB1 = bfhi(zB);
        float aA0 = 0.f, aA1 = 0.f, bA0 = 0.f, bA1 = 0.f;
        float aB0 = 0.f, aB1 = 0.f, bB0 = 0.f, bB1 = 0.f;
        #pragma unroll
        for (int e = 0; e < 16; ++e) {
            const int sA = epA[e], sB = epB[e];
            uint32_t xA = xb[(size_t)sA * 64 + lane];
            uint32_t xB = xb[(size_t)sB * 64 + lane];
            uint32_t yA = *reinterpret_cast<const uint16_t*>(y8 + (size_t)sA * 128 + 2 * lane);
            uint32_t yB = *reinterpret_cast<const uint16_t*>(y8 + (size_t)sB * 128 + 2 * lane);
            f32x2 pA = __builtin_amdgcn_cvt_pk_f32_fp8((int)yA, false);   // (y'_{2l}, y'_{2l+1})
            f32x2 pB = __builtin_amdgcn_cvt_pk_f32_fp8((int)yB, false);
            float gA0 = __builtin_amdgcn_rcpf(1.f + __builtin_amdgcn_exp2f(zA0 + pA.x));
            float gA1 = __builtin_amdgcn_rcpf(1.f + __builtin_amdgcn_exp2f(zA1 + pA.y));
            float gB0 = __builtin_amdgcn_rcpf(1.f + __builtin_amdgcn_exp2f(zB0 + pB.x));
            float gB1 = __builtin_amdgcn_rcpf(1.f + __builtin_amdgcn_exp2f(zB1 + pB.y));
            if (e & 1) { bA0 += gA0 * bflo(xA); bA1 += gA1 * bfhi(xA); bB0 += gB0 * bflo(xB); bB1 += gB1 * bfhi(xB); }
            else       { aA0 += gA0 * bflo(xA); aA1 += gA1 * bfhi(xA); aB0 += gB0 * bflo(xB); aB1 += gB1 * bfhi(xB); }
        }
        float xA0 = bflo(cAw) + aA0 + bA0, xA1 = bfhi(cAw) + aA1 + bA1;
        float xB0 = bflo(cBw) + aB0 + bB0, xB1 = bfhi(cBw) + aB1 + bB1;
        xnb[(size_t)nuA * 64 + lane] = (uint32_t)(uint16_t)f2bf_s(xA0) | ((uint32_t)(uint16_t)f2bf_s(xA1) << 16);
        xnb[(size_t)nuB * 64 + lane] = (uint32_t)(uint16_t)f2bf_s(xB0) | ((uint32_t)(uint16_t)f2bf_s(xB1) << 16);
    }
}

// out = (sum_e adj*x_new[src]) @ weight + bias. Block = 16 nodes, 4 waves x 4 nodes.
// Phase A: adj-weighted gather of x_new bf16 rows -> xn LDS. Phase B: [16x128]@[128x128]
// MFMA with fused bias.
__global__ __launch_bounds__(256) void out_k(const uint32_t* __restrict__ xnb,
                                             const float* __restrict__ adj,
                                             const int* __restrict__ esrc,
                                             const short* __restrict__ wpack,
                                             const float* __restrict__ bias,
                                             float* __restrict__ out) {
    __shared__ float xn[16 * 132];
    const int tid = threadIdx.x, wave = tid >> 6, lane = tid & 63;
    const int q = lane >> 4, m = lane & 15;
    const int node0 = blockIdx.x * 16;
    const int wn0 = node0 + wave * 4;

    #pragma unroll
    for (int pr = 0; pr < 2; ++pr) {
        const int nuA = __builtin_amdgcn_readfirstlane(wn0 + pr * 2);
        const int nuB = __builtin_amdgcn_readfirstlane(wn0 + pr * 2 + 1);
        const int* epA = esrc + nuA * DEG;
        const int* epB = esrc + nuB * DEG;
        const float* apA = adj + nuA * DEG;
        const float* apB = adj + nuB * DEG;
        float aA0 = 0.f, aA1 = 0.f, bA0 = 0.f, bA1 = 0.f;
        float aB0 = 0.f, aB1 = 0.f, bB0 = 0.f, bB1 = 0.f;
        #pragma unroll
        for (int e = 0; e < 16; ++e) {
            uint32_t uA = xnb[(size_t)epA[e] * 64 + lane];
            uint32_t uB = xnb[(size_t)epB[e] * 64 + lane];
            float wA = apA[e], wB = apB[e];
            if (e & 1) { bA0 += wA * bflo(uA); bA1 += wA * bfhi(uA); bB0 += wB * bflo(uB); bB1 += wB * bfhi(uB); }
            else       { aA0 += wA * bflo(uA); aA1 += wA * bfhi(uA); aB0 += wB * bflo(uB); aB1 += wB * bfhi(uB); }
        }
        const int rA = wave * 4 + pr * 2, rB = rA + 1;
        f32x2 tA; tA.x = aA0 + bA0; tA.y = aA1 + bA1;
        f32x2 tB; tB.x = aB0 + bB0; tB.y = aB1 + bB1;
        *reinterpret_cast<f32x2*>(&xn[rA * 132 + 2 * lane]) = tA;
        *reinterpret_cast<f32x2*>(&xn[rB * 132 + 2 * lane]) = tB;
    }
    __syncthreads();

    f32x4 sacc[2];
    sacc[0] = (f32x4){0.f, 0.f, 0.f, 0.f};
    sacc[1] = (f32x4){0.f, 0.f, 0.f, 0.f};
    #pragma unroll
    for (int kk = 0; kk < 4; ++kk) {
        const float* p = &xn[m * 132 + kk * 32 + q * 8];
        bf16x8 a;
        a[0]=(__bf16)p[0]; a[1]=(__bf16)p[1]; a[2]=(__bf16)p[2]; a[3]=(__bf16)p[3];
        a[4]=(__bf16)p[4]; a[5]=(__bf16)p[5]; a[6]=(__bf16)p[6]; a[7]=(__bf16)p[7];
        #pragma unroll
        for (int t = 0; t < 2; ++t) {
            int nt = wave * 2 + t;
            s16x8 braw = *reinterpret_cast<const s16x8*>(wpack + ((size_t)(kk * 8 + nt) * 64 + lane) * 8);
            sacc[t] = __builtin_amdgcn_mfma_f32_16x16x32_bf16(a, __builtin_bit_cast(bf16x8, braw), sacc[t], 0, 0, 0);
        }
    }
    #pragma unroll
    for (int t = 0; t < 2; ++t) {
        const int f = (wave * 2 + t) * 16 + m;
        const float bv = bias[f];
        #pragma unroll
        for (int i = 0; i < 4; ++i)
            out[(size_t)(node0 + q * 4 + i) * FD + f] = sacc[t][i] + bv;
    }
}

extern "C" void kernel_launch(void* const* d_in, const int* in_sizes, int n_in,
                              void* d_out, int out_size, void* d_ws, size_t ws_size,
                              hipStream_t stream) {
    const float* x      = (const float*)d_in[0];
    const float* weight = (const float*)d_in[1];
    const float* bias   = (const float*)d_in[2];
    const float* wm     = (const float*)d_in[3];
    const float* adj    = (const float*)d_in[4];
    const int*   esrc   = (const int*)d_in[5];
    // d_in[6] edge_dst unused: dst(e) = e/16 by construction.

    // ws: [0,64K) wmb | [64K,96K) wpack | [96K,+12.8M) zbf | [+12.8M,+25.6M) xnb.
    // d_out scratch phase: [0,12.8M) xb (bf16 x rows) | [12.8M,+6.4M) y8 (fp8 y' rows);
    // both fully consumed by edge_k before out_k overwrites d_out with the real output.
    short*    wmb   = (short*)d_ws;
    short*    wpack = (short*)((char*)d_ws + 65536);
    short*    zbf   = (short*)((char*)d_ws + 98304);
    uint32_t* xnb   = (uint32_t*)((char*)d_ws + 98304 + (size_t)NNODES * FD * 2);
    uint32_t* xb    = (uint32_t*)d_out;
    uint8_t*  y8    = (uint8_t*)d_out + (size_t)NNODES * FD * 2;
    float*    out   = (float*)d_out;

    pack_k <<<128,         256, 0, stream>>>(wm, weight, wmb, wpack);
    zy_k   <<<NNODES / 16, 256, 0, stream>>>(x, wmb, zbf, xb, y8);
    edge_k <<<NNODES / 16, 256, 0, stream>>>(zbf, xb, y8, esrc, xnb);
    out_k  <<<NNODES / 16, 256, 0, stream>>>(xnb, adj, esrc, wpack, bias, out);
}